// Round 13
// baseline (38400.345 us; speedup 1.0000x reference)
//
#include <hip/hip_runtime.h>
#include <hip/hip_bf16.h>

#define H_DIM 356
#define G4 1424            // 4*H
#define NCTX 8192
#define NQ 1024
#define NTOT 9216
#define CDIM 100
#define NFILT 100
#define KW 5
#define WCH 16

typedef _Float16 f16_t;

__device__ __forceinline__ float sigmoidf_fast(float x) {
    return 1.0f / (1.0f + __expf(-x));
}
__device__ __forceinline__ float tanhf_fast(float x) {
    return 2.0f / (1.0f + __expf(-2.0f * x)) - 1.0f;
}
__device__ __forceinline__ unsigned pack_f16x2(float a, float b) {
    _Float16 ha = (_Float16)a, hb = (_Float16)b;
    unsigned short ua = __builtin_bit_cast(unsigned short, ha);
    unsigned short ub = __builtin_bit_cast(unsigned short, hb);
    return (unsigned)ua | ((unsigned)ub << 16);
}
__device__ __forceinline__ unsigned short f16_bits(float a) {
    _Float16 ha = (_Float16)a;
    return __builtin_bit_cast(unsigned short, ha);
}

// v_dot2_f32_f16 with the h-operand in an SGPR (no per-lane copy of h).
// SGPR value comes from __builtin_amdgcn_readlane (vector-coherent path).
#define FDOT_S(ACC, W, HS) \
    asm("v_dot2_f32_f16 %0, %1, %2, %0" : "+v"(ACC) : "v"(W), "s"(HS))

#define AL(P) __hip_atomic_load((P), __ATOMIC_RELAXED, __HIP_MEMORY_SCOPE_AGENT)

// ---------------------------------------------------------------------------
// Kernel 1: char-CNN + maxpool + ELMo concat + 2-layer highway. (unchanged)
// ---------------------------------------------------------------------------
__global__ __launch_bounds__(128) void cnn_highway_kernel(
    const int* __restrict__ ctx_ids, const int* __restrict__ q_ids,
    const float* __restrict__ ctx_elmo, const float* __restrict__ q_elmo,
    const float* __restrict__ char_emb, const float* __restrict__ conv_w,
    const float* __restrict__ conv_b,
    const float* __restrict__ hw_pw, const float* __restrict__ hw_pb,
    const float* __restrict__ hw_gw, const float* __restrict__ hw_gb,
    float* __restrict__ feats_out)
{
    __shared__ float s_ce[WCH][CDIM];
    __shared__ float s_feats[16][H_DIM];
    const int tid  = threadIdx.x;
    const int row0 = blockIdx.x * 16;

    for (int rr = 0; rr < 16; ++rr) {
        const int row = row0 + rr;
        const int* ids = (row < NCTX) ? (ctx_ids + (size_t)row * WCH)
                                      : (q_ids + (size_t)(row - NCTX) * WCH);
        for (int idx = tid; idx < WCH * CDIM; idx += 128) {
            int w = idx / CDIM, c = idx - w * CDIM;
            s_ce[w][c] = char_emb[(size_t)ids[w] * CDIM + c];
        }
        __syncthreads();
        if (tid < NFILT) {
            const int f = tid;
            float s[WCH];
            float bias = conv_b[f];
            #pragma unroll
            for (int p = 0; p < WCH; ++p) s[p] = bias;
            const float* wrow = conv_w + (size_t)f * CDIM * KW;
            for (int c0 = 0; c0 < CDIM; c0 += 4) {
                float wv[20];
                const float4* wp4 = (const float4*)(wrow + c0 * KW);
                #pragma unroll
                for (int u = 0; u < 5; ++u) {
                    float4 v = wp4[u];
                    wv[u * 4 + 0] = v.x; wv[u * 4 + 1] = v.y;
                    wv[u * 4 + 2] = v.z; wv[u * 4 + 3] = v.w;
                }
                #pragma unroll
                for (int cc = 0; cc < 4; ++cc) {
                    float ce[WCH];
                    #pragma unroll
                    for (int w = 0; w < WCH; ++w) ce[w] = s_ce[w][c0 + cc];
                    #pragma unroll
                    for (int p = 0; p < WCH; ++p) {
                        #pragma unroll
                        for (int k = 0; k < KW; ++k) {
                            const int wpos = p + k - 2;
                            if (wpos >= 0 && wpos < WCH)
                                s[p] = fmaf(ce[wpos], wv[cc * 5 + k], s[p]);
                        }
                    }
                }
            }
            float m = s[0];
            #pragma unroll
            for (int p = 1; p < WCH; ++p) m = fmaxf(m, s[p]);
            s_feats[rr][f] = m;
        }
        __syncthreads();
    }

    for (int idx = tid; idx < 16 * 256; idx += 128) {
        int rr = idx >> 8, c = idx & 255;
        int row = row0 + rr;
        float v = (row < NCTX) ? ctx_elmo[(size_t)row * 256 + c]
                               : q_elmo[(size_t)(row - NCTX) * 256 + c];
        s_feats[rr][CDIM + c] = v;
    }
    __syncthreads();

    for (int l = 0; l < 2; ++l) {
        float newv[3][16];
        for (int it = 0; it < 3; ++it) {
            const int j = it * 128 + tid;
            if (j < H_DIM) {
                float accP[16], accG[16];
                #pragma unroll
                for (int r = 0; r < 16; ++r) { accP[r] = 0.0f; accG[r] = 0.0f; }
                const float* pw = hw_pw + ((size_t)l * H_DIM + j) * H_DIM;
                const float* gw = hw_gw + ((size_t)l * H_DIM + j) * H_DIM;
                for (int k0 = 0; k0 < H_DIM; k0 += 4) {
                    float4 wpv4 = *(const float4*)(pw + k0);
                    float4 wgv4 = *(const float4*)(gw + k0);
                    float wp[4] = {wpv4.x, wpv4.y, wpv4.z, wpv4.w};
                    float wg[4] = {wgv4.x, wgv4.y, wgv4.z, wgv4.w};
                    #pragma unroll
                    for (int kk = 0; kk < 4; ++kk) {
                        #pragma unroll
                        for (int r = 0; r < 16; ++r) {
                            float fv = s_feats[r][k0 + kk];
                            accP[r] = fmaf(fv, wp[kk], accP[r]);
                            accG[r] = fmaf(fv, wg[kk], accG[r]);
                        }
                    }
                }
                const float pb = hw_pb[l * H_DIM + j];
                const float gb = hw_gb[l * H_DIM + j];
                #pragma unroll
                for (int r = 0; r < 16; ++r) {
                    float p = accP[r] + pb; p = p > 0.0f ? p : 0.0f;
                    float g = sigmoidf_fast(accG[r] + gb);
                    newv[it][r] = g * p + (1.0f - g) * s_feats[r][j];
                }
            }
        }
        __syncthreads();
        for (int it = 0; it < 3; ++it) {
            const int j = it * 128 + tid;
            if (j < H_DIM) {
                #pragma unroll
                for (int r = 0; r < 16; ++r) s_feats[r][j] = newv[it][r];
            }
        }
        __syncthreads();
    }

    for (int idx = tid; idx < 16 * H_DIM; idx += 128) {
        int rr = idx / H_DIM, j = idx - rr * H_DIM;
        feats_out[(size_t)(row0 + rr) * H_DIM + j] = s_feats[rr][j];
    }
}

// ---------------------------------------------------------------------------
// Kernel 2: C[z][m][n] = A[m][:] . B[z][n][:] + bias, f16 output. (unchanged)
// ---------------------------------------------------------------------------
__global__ __launch_bounds__(256) void gemm_nt_bias_kernel(
    const float* __restrict__ A, const float* __restrict__ B,
    const float* __restrict__ bia, const float* __restrict__ bib,
    f16_t* __restrict__ C, int M, int N, int K)
{
    const int z = blockIdx.z;
    const float* Bz = B + (size_t)z * N * K;
    f16_t* Cz = C + (size_t)z * M * N;
    const int n0 = blockIdx.x * 64;
    const int m0 = blockIdx.y * 64;
    __shared__ float As[64][17];
    __shared__ float Bs[64][17];
    const int tid = threadIdx.x;
    const int tx = tid & 15, ty = tid >> 4;
    const int lr = tid >> 2;
    const int lc = (tid & 3) * 4;
    float acc[4][4];
    #pragma unroll
    for (int i = 0; i < 4; ++i)
        #pragma unroll
        for (int j = 0; j < 4; ++j) acc[i][j] = 0.0f;

    const int ktiles = (K + 15) / 16;
    for (int kt = 0; kt < ktiles; ++kt) {
        const int k0 = kt * 16;
        float4 av = {0, 0, 0, 0}, bv = {0, 0, 0, 0};
        if (k0 + lc < K)
            av = *(const float4*)(A + (size_t)(m0 + lr) * K + k0 + lc);
        const int bn = n0 + lr;
        if (bn < N && k0 + lc < K)
            bv = *(const float4*)(Bz + (size_t)bn * K + k0 + lc);
        __syncthreads();
        As[lr][lc + 0] = av.x; As[lr][lc + 1] = av.y;
        As[lr][lc + 2] = av.z; As[lr][lc + 3] = av.w;
        Bs[lr][lc + 0] = bv.x; Bs[lr][lc + 1] = bv.y;
        Bs[lr][lc + 2] = bv.z; Bs[lr][lc + 3] = bv.w;
        __syncthreads();
        #pragma unroll
        for (int kk = 0; kk < 16; ++kk) {
            float a[4], b[4];
            #pragma unroll
            for (int i = 0; i < 4; ++i) a[i] = As[ty * 4 + i][kk];
            #pragma unroll
            for (int j = 0; j < 4; ++j) b[j] = Bs[tx * 4 + j][kk];
            #pragma unroll
            for (int i = 0; i < 4; ++i)
                #pragma unroll
                for (int j = 0; j < 4; ++j)
                    acc[i][j] = fmaf(a[i], b[j], acc[i][j]);
        }
    }
    #pragma unroll
    for (int j = 0; j < 4; ++j) {
        const int n = n0 + tx * 4 + j;
        if (n < N) {
            const float bsum = bia[(size_t)z * N + n] + bib[(size_t)z * N + n];
            #pragma unroll
            for (int i = 0; i < 4; ++i) {
                const int m = m0 + ty * 4 + i;
                Cz[(size_t)m * N + n] = (f16_t)(acc[i][j] + bsum);
            }
        }
    }
}

// ---------------------------------------------------------------------------
// Kernel 3: LSTM scan — round-7 chassis (best measured: 15.3ms steady;
// rounds 8-12's structural variants were all neutral or worse) + two
// latency-only deltas targeting the measured floor (per-step = MALL
// visibility Λ ~3000cy + dot ~1150cy + cell/barriers):
//  (1) 2-DEEP PIPELINED POLL: issue the next 4-word batch before checking
//      the current one -> detect = visibility + ~0.5 load-latency instead
//      of +1.5 (saves ~400-800cy/step).
//  (2) lgkmcnt-only barriers (both barrier deps are LDS-only) -> the
//      discarded in-flight poll loads from (1) are NOT drained at each
//      barrier; round 10's regression came from its prefetch+NT traffic,
//      not this barrier form.
// Protocol (tagged words, padded slices, readlane->v_dot2 scalar-src,
// agent-scope relaxed atomics) byte-identical to round 7.
// ---------------------------------------------------------------------------
__global__ __launch_bounds__(768)
__attribute__((amdgpu_waves_per_eu(3, 3)))
void lstm_scan8_kernel(
    const f16_t* __restrict__ xg,    // [2][9216][1424] f16, biases folded
    const float* __restrict__ whh,   // [2][1424][356] f32
    const float* __restrict__ h0,    // [2][356]
    const float* __restrict__ c0,    // [2][356]
    float* __restrict__ out,         // [9216][712]
    unsigned* hbuf,                  // tagged states [sum(T+1)][384] u32
    int tagbase)
{
    const int bid = blockIdx.x;
    const int s = bid & 7;
    if (s >= 4) return;
    const int sub = bid >> 3;                    // 0..7
    const int doc = s >> 1, dir = s & 1;
    const int T = doc ? NQ : NCTX;
    const int rbase = doc ? NCTX : 0;
    const int soff = (s == 0) ? 0 : (s == 1) ? 8193 : (s == 2) ? 16386 : 17411;
    unsigned* hb = hbuf + (size_t)soff * 384;
    const int cnt = (sub < 4) ? 45 : 44;
    const int os  = 44 * sub + (sub < 4 ? sub : 4);
    const int tid = threadIdx.x;
    const int lane = tid & 63;

    __shared__ float s_part[4][192];

    const int wvi = tid >> 6;                    // 0..11
    const int qd  = wvi & 3;                     // quarter / slice
    const int rgp = wvi >> 2;                    // 0..2
    const int r   = rgp * 64 + lane;             // 0..191
    const bool act = (r < 4 * cnt);
    const int gate = act ? (r / cnt) : 0;
    const int off  = act ? (r - gate * cnt) : 0;
    const int grow = gate * H_DIM + os + off;    // gate row within dir

    // ---- stage quarter qd of gate row grow: 48 packed-f16x2 VGPRs ----
    unsigned w[48];
    if (act) {
        const float* wrow = whh + ((size_t)dir * G4 + grow) * H_DIM + 89 * qd;
        #pragma unroll
        for (int p = 0; p < 44; ++p)
            w[p] = pack_f16x2(wrow[2 * p], wrow[2 * p + 1]);
        w[44] = pack_f16x2(wrow[88], 0.0f);
        w[45] = 0u; w[46] = 0u; w[47] = 0u;
    } else {
        #pragma unroll
        for (int p = 0; p < 48; ++p) w[p] = 0u;
    }

    // ---- publication word index (computed once) ----
    const int npub = cnt + (sub < 4 ? 7 : 0);    // outputs + pad words
    int pubw = 0;
    if (tid < npub) {
        if (tid < cnt) {
            const int i = os + tid;
            pubw = 96 * (i / 89) + (i % 89);
        } else {
            pubw = 96 * sub + 89 + (tid - cnt);  // pads of slice `sub`
        }
    }

    // ---- init state: publish tagged h0 slice ----
    float c_state = 0.0f;
    if (tid < npub) {
        unsigned short hv = 0;
        if (tid < cnt) {
            c_state = c0[dir * H_DIM + os + tid];
            hv = f16_bits(h0[dir * H_DIM + os + tid]);
        }
        __hip_atomic_store(&hb[pubw], ((unsigned)(tagbase + 1) << 16) | hv,
                           __ATOMIC_RELAXED, __HIP_MEMORY_SCOPE_AGENT);
    }

    const f16_t* xgd = xg + (size_t)dir * NTOT * G4;
    const int kb = (lane < 24) ? 4 * lane : 92;

    for (int t = 0; t < T; ++t) {
        const int row = rbase + (dir ? (T - 1 - t) : t);
        // xg seed (quarter 0 only) — issued before the poll to overlap latency
        float xv = 0.0f;
        if (qd == 0 && act) xv = (float)xgd[(size_t)row * G4 + grow];

        // (1) 2-deep pipelined poll of own 4 tagged words of slice qd
        const unsigned want = (unsigned)(tagbase + t + 1);
        const unsigned* hw_ = hb + (size_t)t * 384 + 96 * qd;
        unsigned w0 = AL(&hw_[kb]),     w1 = AL(&hw_[kb + 1]),
                 w2 = AL(&hw_[kb + 2]), w3 = AL(&hw_[kb + 3]);
        for (;;) {
            // issue next batch before evaluating the current one
            unsigned x0 = AL(&hw_[kb]),     x1 = AL(&hw_[kb + 1]),
                     x2 = AL(&hw_[kb + 2]), x3 = AL(&hw_[kb + 3]);
            if (((w0 >> 16) == want) & ((w1 >> 16) == want) &
                ((w2 >> 16) == want) & ((w3 >> 16) == want)) break;
            w0 = AL(&hw_[kb]);     w1 = AL(&hw_[kb + 1]);
            w2 = AL(&hw_[kb + 2]); w3 = AL(&hw_[kb + 3]);
            if (((x0 >> 16) == want) & ((x1 >> 16) == want) &
                ((x2 >> 16) == want) & ((x3 >> 16) == want)) {
                w0 = x0; w1 = x1; w2 = x2; w3 = x3; break;
            }
        }
        // pair in vector domain: lane L holds pairs 2L (p0) and 2L+1 (p1)
        const unsigned p0 = (w0 & 0xffffu) | (w1 << 16);
        const unsigned p1 = (w2 & 0xffffu) | (w3 << 16);

        // dot over this quarter: pair q -> lane q>>1, even->p0 odd->p1
        float a0 = xv, a1 = 0.0f, a2 = 0.0f, a3 = 0.0f;
        #pragma unroll
        for (int q = 0; q < 48; q += 4) {
            const unsigned h0q = __builtin_amdgcn_readlane(p0, (q >> 1));
            const unsigned h1q = __builtin_amdgcn_readlane(p1, (q >> 1));
            const unsigned h2q = __builtin_amdgcn_readlane(p0, (q >> 1) + 1);
            const unsigned h3q = __builtin_amdgcn_readlane(p1, (q >> 1) + 1);
            FDOT_S(a0, w[q],     h0q);
            FDOT_S(a1, w[q + 1], h1q);
            FDOT_S(a2, w[q + 2], h2q);
            FDOT_S(a3, w[q + 3], h3q);
        }
        if (act) s_part[qd][r] = (a0 + a1) + (a2 + a3);

        // (2) barrier A: drain LDS only; in-flight discarded polls survive
        asm volatile("s_waitcnt lgkmcnt(0)" ::: "memory");
        __builtin_amdgcn_sched_barrier(0);
        __builtin_amdgcn_s_barrier();
        __builtin_amdgcn_sched_barrier(0);

        // cell update for the cnt owned outputs (+pad publishers)
        if (tid < npub) {
            unsigned short hvbits = 0;
            float hh = 0.0f;
            if (tid < cnt) {
                const float gi = s_part[0][tid] + s_part[1][tid]
                               + s_part[2][tid] + s_part[3][tid];
                const float gf = s_part[0][cnt + tid] + s_part[1][cnt + tid]
                               + s_part[2][cnt + tid] + s_part[3][cnt + tid];
                const float gg = s_part[0][2*cnt + tid] + s_part[1][2*cnt + tid]
                               + s_part[2][2*cnt + tid] + s_part[3][2*cnt + tid];
                const float go = s_part[0][3*cnt + tid] + s_part[1][3*cnt + tid]
                               + s_part[2][3*cnt + tid] + s_part[3][3*cnt + tid];
                const float ii = sigmoidf_fast(gi);
                const float ff = sigmoidf_fast(gf);
                const float gt = tanhf_fast(gg);
                const float oo = sigmoidf_fast(go);
                c_state = ff * c_state + ii * gt;
                hh = oo * tanhf_fast(c_state);
                hvbits = f16_bits(hh);
            }
            __hip_atomic_store(&hb[(size_t)(t + 1) * 384 + pubw],
                               ((unsigned)(tagbase + t + 2) << 16) | hvbits,
                               __ATOMIC_RELAXED, __HIP_MEMORY_SCOPE_AGENT);
            if (tid < cnt)
                out[(size_t)row * 712 + dir * H_DIM + os + tid] = hh;
        }
        // (2) barrier B: protect s_part from next step's overwrite (LDS-only)
        asm volatile("s_waitcnt lgkmcnt(0)" ::: "memory");
        __builtin_amdgcn_sched_barrier(0);
        __builtin_amdgcn_s_barrier();
        __builtin_amdgcn_sched_barrier(0);
    }
}

// ---------------------------------------------------------------------------
extern "C" void kernel_launch(void* const* d_in, const int* in_sizes, int n_in,
                              void* d_out, int out_size, void* d_ws, size_t ws_size,
                              hipStream_t stream) {
    (void)in_sizes; (void)n_in; (void)out_size; (void)ws_size;
    const int*   ctx_ids  = (const int*)d_in[0];
    const int*   q_ids    = (const int*)d_in[1];
    const float* ctx_elmo = (const float*)d_in[2];
    const float* q_elmo   = (const float*)d_in[3];
    const float* char_emb = (const float*)d_in[4];
    const float* conv_w   = (const float*)d_in[5];
    const float* conv_b   = (const float*)d_in[6];
    const float* hw_pw    = (const float*)d_in[7];
    const float* hw_pb    = (const float*)d_in[8];
    const float* hw_gw    = (const float*)d_in[9];
    const float* hw_gb    = (const float*)d_in[10];
    const float* w_ih0    = (const float*)d_in[11];
    const float* w_hh0    = (const float*)d_in[12];
    const float* b_ih0    = (const float*)d_in[13];
    const float* b_hh0    = (const float*)d_in[14];
    const float* w_ih1    = (const float*)d_in[15];
    const float* w_hh1    = (const float*)d_in[16];
    const float* b_ih1    = (const float*)d_in[17];
    const float* b_hh1    = (const float*)d_in[18];
    const float* h0       = (const float*)d_in[19];
    const float* c0       = (const float*)d_in[20];
    float* out = (float*)d_out;

    // ws layout (bytes):
    //   xg    f16  52,494,336
    //   feats f32  13,123,584
    //   l1out f32  26,247,168
    //   hbuf  u32  28,317,696   (18436 slots x 384 tagged words, both layers)
    //   total ~120.2 MB
    f16_t* xg    = (f16_t*)d_ws;
    float* feats = (float*)((char*)d_ws + (size_t)2 * NTOT * G4 * sizeof(f16_t));
    float* l1out = feats + (size_t)NTOT * H_DIM;
    unsigned* hbuf = (unsigned*)(l1out + (size_t)NTOT * 712);

    (void)hipMemsetAsync(hbuf, 0, (size_t)18436 * 384 * sizeof(unsigned),
                         stream);

    cnn_highway_kernel<<<NTOT / 16, 128, 0, stream>>>(
        ctx_ids, q_ids, ctx_elmo, q_elmo, char_emb, conv_w, conv_b,
        hw_pw, hw_pb, hw_gw, hw_gb, feats);

    dim3 ggrid((G4 + 63) / 64, NTOT / 64, 2);
    gemm_nt_bias_kernel<<<ggrid, 256, 0, stream>>>(
        feats, w_ih0, b_ih0, b_hh0, xg, NTOT, G4, H_DIM);

    lstm_scan8_kernel<<<64, 768, 0, stream>>>(
        xg, w_hh0, h0, c0, l1out, hbuf, 0);

    gemm_nt_bias_kernel<<<ggrid, 256, 0, stream>>>(
        l1out, w_ih1, b_ih1, b_hh1, xg, NTOT, G4, 2 * H_DIM);

    lstm_scan8_kernel<<<64, 768, 0, stream>>>(
        xg, w_hh1, h0 + 2 * H_DIM, c0 + 2 * H_DIM, out, hbuf, 16384);
}

// Round 14
// 31188.800 us; speedup vs baseline: 1.2312x; 1.2312x over previous
//
#include <hip/hip_runtime.h>
#include <hip/hip_bf16.h>

#define H_DIM 356
#define G4 1424            // 4*H
#define NCTX 8192
#define NQ 1024
#define NTOT 9216
#define CDIM 100
#define NFILT 100
#define KW 5
#define WCH 16

typedef _Float16 f16_t;

__device__ __forceinline__ float sigmoidf_fast(float x) {
    return 1.0f / (1.0f + __expf(-x));
}
__device__ __forceinline__ float tanhf_fast(float x) {
    return 2.0f / (1.0f + __expf(-2.0f * x)) - 1.0f;
}
__device__ __forceinline__ unsigned pack_f16x2(float a, float b) {
    _Float16 ha = (_Float16)a, hb = (_Float16)b;
    unsigned short ua = __builtin_bit_cast(unsigned short, ha);
    unsigned short ub = __builtin_bit_cast(unsigned short, hb);
    return (unsigned)ua | ((unsigned)ub << 16);
}
__device__ __forceinline__ unsigned short f16_bits(float a) {
    _Float16 ha = (_Float16)a;
    return __builtin_bit_cast(unsigned short, ha);
}

// v_dot2_f32_f16 with the h-operand in an SGPR (no per-lane copy of h).
// SGPR value comes from __builtin_amdgcn_readlane (vector-coherent path).
#define FDOT_S(ACC, W, HS) \
    asm("v_dot2_f32_f16 %0, %1, %2, %0" : "+v"(ACC) : "v"(W), "s"(HS))

// ---------------------------------------------------------------------------
// Kernel 1: char-CNN + maxpool + ELMo concat + 2-layer highway.
// ---------------------------------------------------------------------------
__global__ __launch_bounds__(128) void cnn_highway_kernel(
    const int* __restrict__ ctx_ids, const int* __restrict__ q_ids,
    const float* __restrict__ ctx_elmo, const float* __restrict__ q_elmo,
    const float* __restrict__ char_emb, const float* __restrict__ conv_w,
    const float* __restrict__ conv_b,
    const float* __restrict__ hw_pw, const float* __restrict__ hw_pb,
    const float* __restrict__ hw_gw, const float* __restrict__ hw_gb,
    float* __restrict__ feats_out)
{
    __shared__ float s_ce[WCH][CDIM];
    __shared__ float s_feats[16][H_DIM];
    const int tid  = threadIdx.x;
    const int row0 = blockIdx.x * 16;

    for (int rr = 0; rr < 16; ++rr) {
        const int row = row0 + rr;
        const int* ids = (row < NCTX) ? (ctx_ids + (size_t)row * WCH)
                                      : (q_ids + (size_t)(row - NCTX) * WCH);
        for (int idx = tid; idx < WCH * CDIM; idx += 128) {
            int w = idx / CDIM, c = idx - w * CDIM;
            s_ce[w][c] = char_emb[(size_t)ids[w] * CDIM + c];
        }
        __syncthreads();
        if (tid < NFILT) {
            const int f = tid;
            float s[WCH];
            float bias = conv_b[f];
            #pragma unroll
            for (int p = 0; p < WCH; ++p) s[p] = bias;
            const float* wrow = conv_w + (size_t)f * CDIM * KW;
            for (int c0 = 0; c0 < CDIM; c0 += 4) {
                float wv[20];
                const float4* wp4 = (const float4*)(wrow + c0 * KW);
                #pragma unroll
                for (int u = 0; u < 5; ++u) {
                    float4 v = wp4[u];
                    wv[u * 4 + 0] = v.x; wv[u * 4 + 1] = v.y;
                    wv[u * 4 + 2] = v.z; wv[u * 4 + 3] = v.w;
                }
                #pragma unroll
                for (int cc = 0; cc < 4; ++cc) {
                    float ce[WCH];
                    #pragma unroll
                    for (int w = 0; w < WCH; ++w) ce[w] = s_ce[w][c0 + cc];
                    #pragma unroll
                    for (int p = 0; p < WCH; ++p) {
                        #pragma unroll
                        for (int k = 0; k < KW; ++k) {
                            const int wpos = p + k - 2;
                            if (wpos >= 0 && wpos < WCH)
                                s[p] = fmaf(ce[wpos], wv[cc * 5 + k], s[p]);
                        }
                    }
                }
            }
            float m = s[0];
            #pragma unroll
            for (int p = 1; p < WCH; ++p) m = fmaxf(m, s[p]);
            s_feats[rr][f] = m;
        }
        __syncthreads();
    }

    for (int idx = tid; idx < 16 * 256; idx += 128) {
        int rr = idx >> 8, c = idx & 255;
        int row = row0 + rr;
        float v = (row < NCTX) ? ctx_elmo[(size_t)row * 256 + c]
                               : q_elmo[(size_t)(row - NCTX) * 256 + c];
        s_feats[rr][CDIM + c] = v;
    }
    __syncthreads();

    for (int l = 0; l < 2; ++l) {
        float newv[3][16];
        for (int it = 0; it < 3; ++it) {
            const int j = it * 128 + tid;
            if (j < H_DIM) {
                float accP[16], accG[16];
                #pragma unroll
                for (int r = 0; r < 16; ++r) { accP[r] = 0.0f; accG[r] = 0.0f; }
                const float* pw = hw_pw + ((size_t)l * H_DIM + j) * H_DIM;
                const float* gw = hw_gw + ((size_t)l * H_DIM + j) * H_DIM;
                for (int k0 = 0; k0 < H_DIM; k0 += 4) {
                    float4 wpv4 = *(const float4*)(pw + k0);
                    float4 wgv4 = *(const float4*)(gw + k0);
                    float wp[4] = {wpv4.x, wpv4.y, wpv4.z, wpv4.w};
                    float wg[4] = {wgv4.x, wgv4.y, wgv4.z, wgv4.w};
                    #pragma unroll
                    for (int kk = 0; kk < 4; ++kk) {
                        #pragma unroll
                        for (int r = 0; r < 16; ++r) {
                            float fv = s_feats[r][k0 + kk];
                            accP[r] = fmaf(fv, wp[kk], accP[r]);
                            accG[r] = fmaf(fv, wg[kk], accG[r]);
                        }
                    }
                }
                const float pb = hw_pb[l * H_DIM + j];
                const float gb = hw_gb[l * H_DIM + j];
                #pragma unroll
                for (int r = 0; r < 16; ++r) {
                    float p = accP[r] + pb; p = p > 0.0f ? p : 0.0f;
                    float g = sigmoidf_fast(accG[r] + gb);
                    newv[it][r] = g * p + (1.0f - g) * s_feats[r][j];
                }
            }
        }
        __syncthreads();
        for (int it = 0; it < 3; ++it) {
            const int j = it * 128 + tid;
            if (j < H_DIM) {
                #pragma unroll
                for (int r = 0; r < 16; ++r) s_feats[r][j] = newv[it][r];
            }
        }
        __syncthreads();
    }

    for (int idx = tid; idx < 16 * H_DIM; idx += 128) {
        int rr = idx / H_DIM, j = idx - rr * H_DIM;
        feats_out[(size_t)(row0 + rr) * H_DIM + j] = s_feats[rr][j];
    }
}

// ---------------------------------------------------------------------------
// Kernel 2: C[z][m][n] = A[m][:] . B[z][n][:] + bias, f16 output.
// ---------------------------------------------------------------------------
__global__ __launch_bounds__(256) void gemm_nt_bias_kernel(
    const float* __restrict__ A, const float* __restrict__ B,
    const float* __restrict__ bia, const float* __restrict__ bib,
    f16_t* __restrict__ C, int M, int N, int K)
{
    const int z = blockIdx.z;
    const float* Bz = B + (size_t)z * N * K;
    f16_t* Cz = C + (size_t)z * M * N;
    const int n0 = blockIdx.x * 64;
    const int m0 = blockIdx.y * 64;
    __shared__ float As[64][17];
    __shared__ float Bs[64][17];
    const int tid = threadIdx.x;
    const int tx = tid & 15, ty = tid >> 4;
    const int lr = tid >> 2;
    const int lc = (tid & 3) * 4;
    float acc[4][4];
    #pragma unroll
    for (int i = 0; i < 4; ++i)
        #pragma unroll
        for (int j = 0; j < 4; ++j) acc[i][j] = 0.0f;

    const int ktiles = (K + 15) / 16;
    for (int kt = 0; kt < ktiles; ++kt) {
        const int k0 = kt * 16;
        float4 av = {0, 0, 0, 0}, bv = {0, 0, 0, 0};
        if (k0 + lc < K)
            av = *(const float4*)(A + (size_t)(m0 + lr) * K + k0 + lc);
        const int bn = n0 + lr;
        if (bn < N && k0 + lc < K)
            bv = *(const float4*)(Bz + (size_t)bn * K + k0 + lc);
        __syncthreads();
        As[lr][lc + 0] = av.x; As[lr][lc + 1] = av.y;
        As[lr][lc + 2] = av.z; As[lr][lc + 3] = av.w;
        Bs[lr][lc + 0] = bv.x; Bs[lr][lc + 1] = bv.y;
        Bs[lr][lc + 2] = bv.z; Bs[lr][lc + 3] = bv.w;
        __syncthreads();
        #pragma unroll
        for (int kk = 0; kk < 16; ++kk) {
            float a[4], b[4];
            #pragma unroll
            for (int i = 0; i < 4; ++i) a[i] = As[ty * 4 + i][kk];
            #pragma unroll
            for (int j = 0; j < 4; ++j) b[j] = Bs[tx * 4 + j][kk];
            #pragma unroll
            for (int i = 0; i < 4; ++i)
                #pragma unroll
                for (int j = 0; j < 4; ++j)
                    acc[i][j] = fmaf(a[i], b[j], acc[i][j]);
        }
    }
    #pragma unroll
    for (int j = 0; j < 4; ++j) {
        const int n = n0 + tx * 4 + j;
        if (n < N) {
            const float bsum = bia[(size_t)z * N + n] + bib[(size_t)z * N + n];
            #pragma unroll
            for (int i = 0; i < 4; ++i) {
                const int m = m0 + ty * 4 + i;
                Cz[(size_t)m * N + n] = (f16_t)(acc[i][j] + bsum);
            }
        }
    }
}

// ---------------------------------------------------------------------------
// Kernel 3: LSTM scan — ROUND-7 KERNEL, verbatim (best measured: 15.3ms
// steady, 32.4ms total). 8 blocks/scan, quarter-row/thread (48 packed-f16x2
// VGPRs, resident at VGPR_Count=68), tagged-word exchange via agent-scope
// relaxed atomics (the only architecturally sanctioned cross-CU path on
// gfx95x — rounds 8-13 falsified every shortcut: RMW prefetch, NT stores,
// lgkmcnt-only barriers, sc0 same-XCD L2, poll dedup, cell overlap,
// pipelined poll; all neutral or regressions). Per-step floor = MALL
// visibility Λ≈1.4-1.5µs + compute≈0.45µs.
// ---------------------------------------------------------------------------
__global__ __launch_bounds__(768)
__attribute__((amdgpu_waves_per_eu(3, 3)))
void lstm_scan8_kernel(
    const f16_t* __restrict__ xg,    // [2][9216][1424] f16, biases folded
    const float* __restrict__ whh,   // [2][1424][356] f32
    const float* __restrict__ h0,    // [2][356]
    const float* __restrict__ c0,    // [2][356]
    float* __restrict__ out,         // [9216][712]
    unsigned* hbuf,                  // tagged states [sum(T+1)][384] u32
    int tagbase)
{
    const int bid = blockIdx.x;
    const int s = bid & 7;
    if (s >= 4) return;
    const int sub = bid >> 3;                    // 0..7
    const int doc = s >> 1, dir = s & 1;
    const int T = doc ? NQ : NCTX;
    const int rbase = doc ? NCTX : 0;
    const int soff = (s == 0) ? 0 : (s == 1) ? 8193 : (s == 2) ? 16386 : 17411;
    unsigned* hb = hbuf + (size_t)soff * 384;
    const int cnt = (sub < 4) ? 45 : 44;
    const int os  = 44 * sub + (sub < 4 ? sub : 4);
    const int tid = threadIdx.x;
    const int lane = tid & 63;

    __shared__ float s_part[4][192];

    const int wvi = tid >> 6;                    // 0..11
    const int qd  = wvi & 3;                     // quarter / slice
    const int rgp = wvi >> 2;                    // 0..2
    const int r   = rgp * 64 + lane;             // 0..191
    const bool act = (r < 4 * cnt);
    const int gate = act ? (r / cnt) : 0;
    const int off  = act ? (r - gate * cnt) : 0;
    const int grow = gate * H_DIM + os + off;    // gate row within dir

    // ---- stage quarter qd of gate row grow: 48 packed-f16x2 VGPRs ----
    unsigned w[48];
    if (act) {
        const float* wrow = whh + ((size_t)dir * G4 + grow) * H_DIM + 89 * qd;
        #pragma unroll
        for (int p = 0; p < 44; ++p)
            w[p] = pack_f16x2(wrow[2 * p], wrow[2 * p + 1]);
        w[44] = pack_f16x2(wrow[88], 0.0f);
        w[45] = 0u; w[46] = 0u; w[47] = 0u;
    } else {
        #pragma unroll
        for (int p = 0; p < 48; ++p) w[p] = 0u;
    }

    // ---- publication word index (computed once) ----
    const int npub = cnt + (sub < 4 ? 7 : 0);    // outputs + pad words
    int pubw = 0;
    if (tid < npub) {
        if (tid < cnt) {
            const int i = os + tid;
            pubw = 96 * (i / 89) + (i % 89);
        } else {
            pubw = 96 * sub + 89 + (tid - cnt);  // pads of slice `sub`
        }
    }

    // ---- init state: publish tagged h0 slice ----
    float c_state = 0.0f;
    if (tid < npub) {
        unsigned short hv = 0;
        if (tid < cnt) {
            c_state = c0[dir * H_DIM + os + tid];
            hv = f16_bits(h0[dir * H_DIM + os + tid]);
        }
        __hip_atomic_store(&hb[pubw], ((unsigned)(tagbase + 1) << 16) | hv,
                           __ATOMIC_RELAXED, __HIP_MEMORY_SCOPE_AGENT);
    }

    const f16_t* xgd = xg + (size_t)dir * NTOT * G4;

    for (int t = 0; t < T; ++t) {
        const int row = rbase + (dir ? (T - 1 - t) : t);
        // xg seed (quarter 0 only) — issued before the poll to overlap latency
        float xv = 0.0f;
        if (qd == 0 && act) xv = (float)xgd[(size_t)row * G4 + grow];

        // poll own 4 tagged words of slice qd at step t
        const unsigned want = (unsigned)(tagbase + t + 1);
        const unsigned* hw_ = hb + (size_t)t * 384 + 96 * qd;
        const int kb = (lane < 24) ? 4 * lane : 92;
        unsigned w0, w1, w2, w3;
        do {
            w0 = __hip_atomic_load(&hw_[kb],     __ATOMIC_RELAXED,
                                   __HIP_MEMORY_SCOPE_AGENT);
            w1 = __hip_atomic_load(&hw_[kb + 1], __ATOMIC_RELAXED,
                                   __HIP_MEMORY_SCOPE_AGENT);
            w2 = __hip_atomic_load(&hw_[kb + 2], __ATOMIC_RELAXED,
                                   __HIP_MEMORY_SCOPE_AGENT);
            w3 = __hip_atomic_load(&hw_[kb + 3], __ATOMIC_RELAXED,
                                   __HIP_MEMORY_SCOPE_AGENT);
        } while ((w0 >> 16) != want || (w1 >> 16) != want ||
                 (w2 >> 16) != want || (w3 >> 16) != want);
        // pair in vector domain: lane L holds pairs 2L (p0) and 2L+1 (p1)
        const unsigned p0 = (w0 & 0xffffu) | (w1 << 16);
        const unsigned p1 = (w2 & 0xffffu) | (w3 << 16);

        // dot over this quarter: pair q -> lane q>>1, even->p0 odd->p1
        float a0 = xv, a1 = 0.0f, a2 = 0.0f, a3 = 0.0f;
        #pragma unroll
        for (int q = 0; q < 48; q += 4) {
            const unsigned h0q = __builtin_amdgcn_readlane(p0, (q >> 1));
            const unsigned h1q = __builtin_amdgcn_readlane(p1, (q >> 1));
            const unsigned h2q = __builtin_amdgcn_readlane(p0, (q >> 1) + 1);
            const unsigned h3q = __builtin_amdgcn_readlane(p1, (q >> 1) + 1);
            FDOT_S(a0, w[q],     h0q);
            FDOT_S(a1, w[q + 1], h1q);
            FDOT_S(a2, w[q + 2], h2q);
            FDOT_S(a3, w[q + 3], h3q);
        }
        if (act) s_part[qd][r] = (a0 + a1) + (a2 + a3);
        __syncthreads();

        // cell update for the cnt owned outputs (+pad publishers)
        if (tid < npub) {
            unsigned short hvbits = 0;
            float hh = 0.0f;
            if (tid < cnt) {
                const float gi = s_part[0][tid] + s_part[1][tid]
                               + s_part[2][tid] + s_part[3][tid];
                const float gf = s_part[0][cnt + tid] + s_part[1][cnt + tid]
                               + s_part[2][cnt + tid] + s_part[3][cnt + tid];
                const float gg = s_part[0][2*cnt + tid] + s_part[1][2*cnt + tid]
                               + s_part[2][2*cnt + tid] + s_part[3][2*cnt + tid];
                const float go = s_part[0][3*cnt + tid] + s_part[1][3*cnt + tid]
                               + s_part[2][3*cnt + tid] + s_part[3][3*cnt + tid];
                const float ii = sigmoidf_fast(gi);
                const float ff = sigmoidf_fast(gf);
                const float gt = tanhf_fast(gg);
                const float oo = sigmoidf_fast(go);
                c_state = ff * c_state + ii * gt;
                hh = oo * tanhf_fast(c_state);
                hvbits = f16_bits(hh);
            }
            __hip_atomic_store(&hb[(size_t)(t + 1) * 384 + pubw],
                               ((unsigned)(tagbase + t + 2) << 16) | hvbits,
                               __ATOMIC_RELAXED, __HIP_MEMORY_SCOPE_AGENT);
            if (tid < cnt)
                out[(size_t)row * 712 + dir * H_DIM + os + tid] = hh;
        }
        __syncthreads();   // protect s_part from next step's overwrite
    }
}

// ---------------------------------------------------------------------------
extern "C" void kernel_launch(void* const* d_in, const int* in_sizes, int n_in,
                              void* d_out, int out_size, void* d_ws, size_t ws_size,
                              hipStream_t stream) {
    (void)in_sizes; (void)n_in; (void)out_size; (void)ws_size;
    const int*   ctx_ids  = (const int*)d_in[0];
    const int*   q_ids    = (const int*)d_in[1];
    const float* ctx_elmo = (const float*)d_in[2];
    const float* q_elmo   = (const float*)d_in[3];
    const float* char_emb = (const float*)d_in[4];
    const float* conv_w   = (const float*)d_in[5];
    const float* conv_b   = (const float*)d_in[6];
    const float* hw_pw    = (const float*)d_in[7];
    const float* hw_pb    = (const float*)d_in[8];
    const float* hw_gw    = (const float*)d_in[9];
    const float* hw_gb    = (const float*)d_in[10];
    const float* w_ih0    = (const float*)d_in[11];
    const float* w_hh0    = (const float*)d_in[12];
    const float* b_ih0    = (const float*)d_in[13];
    const float* b_hh0    = (const float*)d_in[14];
    const float* w_ih1    = (const float*)d_in[15];
    const float* w_hh1    = (const float*)d_in[16];
    const float* b_ih1    = (const float*)d_in[17];
    const float* b_hh1    = (const float*)d_in[18];
    const float* h0       = (const float*)d_in[19];
    const float* c0       = (const float*)d_in[20];
    float* out = (float*)d_out;

    // ws layout (bytes):
    //   xg    f16  52,494,336
    //   feats f32  13,123,584
    //   l1out f32  26,247,168
    //   hbuf  u32  28,317,696   (18436 slots x 384 tagged words, both layers)
    //   total ~120.2 MB
    f16_t* xg    = (f16_t*)d_ws;
    float* feats = (float*)((char*)d_ws + (size_t)2 * NTOT * G4 * sizeof(f16_t));
    float* l1out = feats + (size_t)NTOT * H_DIM;
    unsigned* hbuf = (unsigned*)(l1out + (size_t)NTOT * 712);

    (void)hipMemsetAsync(hbuf, 0, (size_t)18436 * 384 * sizeof(unsigned),
                         stream);

    cnn_highway_kernel<<<NTOT / 16, 128, 0, stream>>>(
        ctx_ids, q_ids, ctx_elmo, q_elmo, char_emb, conv_w, conv_b,
        hw_pw, hw_pb, hw_gw, hw_gb, feats);

    dim3 ggrid((G4 + 63) / 64, NTOT / 64, 2);
    gemm_nt_bias_kernel<<<ggrid, 256, 0, stream>>>(
        feats, w_ih0, b_ih0, b_hh0, xg, NTOT, G4, H_DIM);

    lstm_scan8_kernel<<<64, 768, 0, stream>>>(
        xg, w_hh0, h0, c0, l1out, hbuf, 0);

    gemm_nt_bias_kernel<<<ggrid, 256, 0, stream>>>(
        l1out, w_ih1, b_ih1, b_hh1, xg, NTOT, G4, 2 * H_DIM);

    lstm_scan8_kernel<<<64, 768, 0, stream>>>(
        xg, w_hh1, h0 + 2 * H_DIM, c0 + 2 * H_DIM, out, hbuf, 16384);
}